// Round 1
// baseline (1293.596 us; speedup 1.0000x reference)
//
#include <hip/hip_runtime.h>
#include <hip/hip_bf16.h>

#define BB 2
#define SS 2048
#define DD 1024
#define HH 16
#define DKK 64
#define NW 256
#define LN_EPS 1e-5f
#define ROWS 16
#define SPAN 528  // >= 15 + 511, padded

// ---------------- GEMM: C[4096][1024] = A[4096][1024] @ W[1024][1024] + bias ----------------
__global__ __launch_bounds__(256) void gemm_proj(
    const float* __restrict__ A, const float* __restrict__ W,
    const float* __restrict__ bias, float* __restrict__ C)
{
    __shared__ float As[16][64];  // [k][m]
    __shared__ float Bs[16][64];  // [k][n]
    const int n0 = blockIdx.x * 64;
    const int m0 = blockIdx.y * 64;
    const int t = threadIdx.x;
    const int tx = t & 15, ty = t >> 4;

    float acc[4][4] = {};
    const int arow = t >> 2, ac4 = (t & 3) * 4;   // A loader: row 0..63, 4 floats
    const int brow = t >> 4, bc4 = (t & 15) * 4;  // B loader: k-row 0..15, 4 floats

    for (int k0 = 0; k0 < 1024; k0 += 16) {
        float4 a4 = *(const float4*)&A[(size_t)(m0 + arow) * 1024 + k0 + ac4];
        As[ac4 + 0][arow] = a4.x;
        As[ac4 + 1][arow] = a4.y;
        As[ac4 + 2][arow] = a4.z;
        As[ac4 + 3][arow] = a4.w;
        *(float4*)&Bs[brow][bc4] = *(const float4*)&W[(size_t)(k0 + brow) * 1024 + n0 + bc4];
        __syncthreads();
#pragma unroll
        for (int k = 0; k < 16; ++k) {
            float4 av = *(const float4*)&As[k][ty * 4];
            float4 bv = *(const float4*)&Bs[k][tx * 4];
            acc[0][0] += av.x * bv.x; acc[0][1] += av.x * bv.y; acc[0][2] += av.x * bv.z; acc[0][3] += av.x * bv.w;
            acc[1][0] += av.y * bv.x; acc[1][1] += av.y * bv.y; acc[1][2] += av.y * bv.z; acc[1][3] += av.y * bv.w;
            acc[2][0] += av.z * bv.x; acc[2][1] += av.z * bv.y; acc[2][2] += av.z * bv.z; acc[2][3] += av.z * bv.w;
            acc[3][0] += av.w * bv.x; acc[3][1] += av.w * bv.y; acc[3][2] += av.w * bv.z; acc[3][3] += av.w * bv.w;
        }
        __syncthreads();
    }
    float4 bb = *(const float4*)&bias[n0 + tx * 4];
#pragma unroll
    for (int i2 = 0; i2 < 4; ++i2) {
        float4 o;
        o.x = acc[i2][0] + bb.x;
        o.y = acc[i2][1] + bb.y;
        o.z = acc[i2][2] + bb.z;
        o.w = acc[i2][3] + bb.w;
        *(float4*)&C[(size_t)(m0 + ty * 4 + i2) * 1024 + n0 + tx * 4] = o;
    }
}

// ---------------- Banded attention: scores, softmax, attn write (full rows), PV ----------------
__global__ __launch_bounds__(256) void attn_kernel(
    const float* __restrict__ qp, const float* __restrict__ kp, const float* __restrict__ vp,
    float* __restrict__ attn, float* __restrict__ ctx)
{
    __shared__ float qs[ROWS][68];
    __shared__ float ks[64][68];      // k tile, later reused as v tile
    __shared__ float sc[ROWS][SPAN];  // whole band of scores/probs

    const int qb = blockIdx.x;  // 0..127
    const int h  = blockIdx.y;  // 0..15
    const int b  = blockIdx.z;  // 0..1
    const int i0 = qb * ROWS;
    const int jlo = max(0, i0 - (NW - 1));
    const int jhi = min(SS, i0 + ROWS - 1 + NW);  // exclusive
    const int width = jhi - jlo;
    const int t = threadIdx.x;

    // load q tile (scaled by 1/sqrt(DK))
    {
        int r = t >> 4;
        int c = (t & 15) * 4;
        float4 v = *(const float4*)&qp[(size_t)(b * SS + i0 + r) * 1024 + h * DKK + c];
        float4 w;
        w.x = v.x * 0.125f; w.y = v.y * 0.125f; w.z = v.z * 0.125f; w.w = v.w * 0.125f;
        *(float4*)&qs[r][c] = w;
    }

    const int sr  = t >> 4;        // score row 0..15
    const int sj4 = (t & 15) * 4;  // 4 consecutive j per thread
    const int lrow = t >> 2;       // k/v loader row 0..63
    const int lc   = (t & 3) * 4;  // loader col base

    // ---- scores over band, tile by tile ----
    for (int jt = jlo; jt < jhi; jt += 64) {
        __syncthreads();  // protect ks from previous iteration readers
        {
            int j = jt + lrow;
#pragma unroll
            for (int mm = 0; mm < 4; ++mm) {
                int c = lc + mm * 16;
                float4 v = make_float4(0.f, 0.f, 0.f, 0.f);
                if (j < jhi) v = *(const float4*)&kp[(size_t)(b * SS + j) * 1024 + h * DKK + c];
                *(float4*)&ks[lrow][c] = v;
            }
        }
        __syncthreads();
        float a0 = 0.f, a1 = 0.f, a2 = 0.f, a3 = 0.f;
#pragma unroll
        for (int d = 0; d < 64; d += 4) {
            float4 q4 = *(const float4*)&qs[sr][d];
            float4 k0 = *(const float4*)&ks[sj4 + 0][d];
            float4 k1 = *(const float4*)&ks[sj4 + 1][d];
            float4 k2 = *(const float4*)&ks[sj4 + 2][d];
            float4 k3 = *(const float4*)&ks[sj4 + 3][d];
            a0 += q4.x * k0.x + q4.y * k0.y + q4.z * k0.z + q4.w * k0.w;
            a1 += q4.x * k1.x + q4.y * k1.y + q4.z * k1.z + q4.w * k1.w;
            a2 += q4.x * k2.x + q4.y * k2.y + q4.z * k2.z + q4.w * k2.w;
            a3 += q4.x * k3.x + q4.y * k3.y + q4.z * k3.z + q4.w * k3.w;
        }
        {
            int i = i0 + sr;
            int j0 = jt + sj4;
            float vals[4] = {a0, a1, a2, a3};
#pragma unroll
            for (int m = 0; m < 4; ++m) {
                int j = j0 + m;
                if (j < jhi) {
                    int di = i - j; di = di < 0 ? -di : di;
                    sc[sr][j - jlo] = (di < NW) ? vals[m] : -1e30f;
                }
            }
        }
    }
    __syncthreads();

    // ---- softmax per row (16 threads per row) ----
    {
        int r = t >> 4;
        int g = t & 15;
        float mx = -1e30f;
        for (int jj = g; jj < width; jj += 16) mx = fmaxf(mx, sc[r][jj]);
#pragma unroll
        for (int off = 1; off < 16; off <<= 1) mx = fmaxf(mx, __shfl_xor(mx, off, 64));
        float sum = 0.f;
        for (int jj = g; jj < width; jj += 16) {
            float e = __expf(sc[r][jj] - mx);
            sc[r][jj] = e;
            sum += e;
        }
#pragma unroll
        for (int off = 1; off < 16; off <<= 1) sum += __shfl_xor(sum, off, 64);
        float inv = 1.0f / sum;
        for (int jj = g; jj < width; jj += 16) sc[r][jj] *= inv;
    }
    __syncthreads();

    // ---- write full attn rows (zeros outside band span) ----
    {
        int r = t >> 4;
        int g = t & 15;
        int i = i0 + r;
        float* arow = attn + (size_t)((b * HH + h) * SS + i) * SS;
#pragma unroll 4
        for (int m = 0; m < 32; ++m) {
            int j4 = (g + 16 * m) * 4;
            float4 o;
            float* pe = &o.x;
#pragma unroll
            for (int e = 0; e < 4; ++e) {
                int jj = j4 + e - jlo;
                pe[e] = (jj >= 0 && jj < width) ? sc[r][jj] : 0.f;
            }
            *(float4*)&arow[j4] = o;
        }
    }

    // ---- PV: ctx[r][d] = sum_j p * v ----
    {
        int r = t >> 4;
        int dg = (t & 15) * 4;
        float4 acc = make_float4(0.f, 0.f, 0.f, 0.f);
        for (int jt = jlo; jt < jhi; jt += 64) {
            __syncthreads();
            {
                int j = jt + lrow;
#pragma unroll
                for (int mm = 0; mm < 4; ++mm) {
                    int c = lc + mm * 16;
                    float4 v = make_float4(0.f, 0.f, 0.f, 0.f);
                    if (j < jhi) v = *(const float4*)&vp[(size_t)(b * SS + j) * 1024 + h * DKK + c];
                    *(float4*)&ks[lrow][c] = v;
                }
            }
            __syncthreads();
            int lim = min(64, jhi - jt);
            int base = jt - jlo;
#pragma unroll 4
            for (int u = 0; u < lim; ++u) {
                float p = sc[r][base + u];
                float4 v4 = *(const float4*)&ks[u][dg];
                acc.x += p * v4.x;
                acc.y += p * v4.y;
                acc.z += p * v4.z;
                acc.w += p * v4.w;
            }
        }
        int i = i0 + r;
        *(float4*)&ctx[(size_t)(b * SS + i) * 1024 + h * DKK + dg] = acc;
    }
}

// ---------------- residual + LayerNorm ----------------
__global__ __launch_bounds__(256) void ln_kernel(
    const float* __restrict__ op, const float* __restrict__ Qin,
    const float* __restrict__ gamma, const float* __restrict__ beta,
    float* __restrict__ y)
{
    const int row = blockIdx.x;
    const int t = threadIdx.x;
    __shared__ float rs[4], rss[4];

    float4 o4 = *(const float4*)&op[(size_t)row * 1024 + t * 4];
    float4 q4 = *(const float4*)&Qin[(size_t)row * 1024 + t * 4];
    float x0 = o4.x + q4.x, x1 = o4.y + q4.y, x2 = o4.z + q4.z, x3 = o4.w + q4.w;
    float s = x0 + x1 + x2 + x3;
    float ss = x0 * x0 + x1 * x1 + x2 * x2 + x3 * x3;
#pragma unroll
    for (int off = 1; off < 64; off <<= 1) {
        s  += __shfl_xor(s, off, 64);
        ss += __shfl_xor(ss, off, 64);
    }
    int wid = t >> 6;
    if ((t & 63) == 0) { rs[wid] = s; rss[wid] = ss; }
    __syncthreads();
    s  = rs[0] + rs[1] + rs[2] + rs[3];
    ss = rss[0] + rss[1] + rss[2] + rss[3];
    float mu = s * (1.0f / 1024.0f);
    float var = ss * (1.0f / 1024.0f) - mu * mu;
    float rstd = rsqrtf(var + LN_EPS);
    float4 g4 = *(const float4*)&gamma[t * 4];
    float4 b4 = *(const float4*)&beta[t * 4];
    float4 o;
    o.x = (x0 - mu) * rstd * g4.x + b4.x;
    o.y = (x1 - mu) * rstd * g4.y + b4.y;
    o.z = (x2 - mu) * rstd * g4.z + b4.z;
    o.w = (x3 - mu) * rstd * g4.w + b4.w;
    *(float4*)&y[(size_t)row * 1024 + t * 4] = o;
}

extern "C" void kernel_launch(void* const* d_in, const int* in_sizes, int n_in,
                              void* d_out, int out_size, void* d_ws, size_t ws_size,
                              hipStream_t stream) {
    (void)in_sizes; (void)n_in; (void)out_size; (void)ws_size;
    const float* Q  = (const float*)d_in[0];
    const float* K  = (const float*)d_in[1];
    const float* V  = (const float*)d_in[2];
    const float* Wq = (const float*)d_in[3];
    const float* bq = (const float*)d_in[4];
    const float* Wk = (const float*)d_in[5];
    const float* bk = (const float*)d_in[6];
    const float* Wv = (const float*)d_in[7];
    const float* bv = (const float*)d_in[8];
    const float* Wo = (const float*)d_in[9];
    const float* bo = (const float*)d_in[10];
    const float* gamma = (const float*)d_in[11];
    const float* beta  = (const float*)d_in[12];

    float* y = (float*)d_out;
    float* attn = y + (size_t)BB * SS * DD;  // 4,194,304 floats

    float* ws  = (float*)d_ws;
    float* qp  = ws;
    float* kp  = ws + (size_t)4194304;
    float* vp  = ws + (size_t)2 * 4194304;
    float* ctx = ws + (size_t)3 * 4194304;
    float* op  = qp;  // q no longer needed after attention

    dim3 gg(16, 64);
    gemm_proj<<<gg, 256, 0, stream>>>(Q, Wq, bq, qp);
    gemm_proj<<<gg, 256, 0, stream>>>(K, Wk, bk, kp);
    gemm_proj<<<gg, 256, 0, stream>>>(V, Wv, bv, vp);
    attn_kernel<<<dim3(SS / ROWS, HH, BB), 256, 0, stream>>>(qp, kp, vp, attn, ctx);
    gemm_proj<<<gg, 256, 0, stream>>>(ctx, Wo, bo, op);
    ln_kernel<<<4096, 256, 0, stream>>>(op, Q, gamma, beta, y);
}

// Round 2
// 809.376 us; speedup vs baseline: 1.5983x; 1.5983x over previous
//
#include <hip/hip_runtime.h>
#include <hip/hip_bf16.h>

#define BB 2
#define SS 2048
#define DD 1024
#define HH 16
#define NW 256
#define LN_EPS 1e-5f

typedef __attribute__((ext_vector_type(8))) short short8;
typedef __attribute__((ext_vector_type(4))) float floatx4;

__device__ __forceinline__ ushort f2b(float f) {
    union { float f; unsigned int u; } x; x.f = f;
    unsigned int u = x.u;
    return (ushort)((u + 0x7FFFu + ((u >> 16) & 1u)) >> 16);
}

// ---------------- W transpose+convert: T[n][k] = bf16(W[k][n]), 1024x1024 ----------------
__global__ __launch_bounds__(256) void wtrans(
    const float* __restrict__ W0, const float* __restrict__ W1,
    const float* __restrict__ W2, const float* __restrict__ W3,
    ushort* __restrict__ T0, ushort* __restrict__ T1,
    ushort* __restrict__ T2, ushort* __restrict__ T3)
{
    const int z = blockIdx.z;
    const float* W = z == 0 ? W0 : z == 1 ? W1 : z == 2 ? W2 : W3;
    ushort* T = z == 0 ? T0 : z == 1 ? T1 : z == 2 ? T2 : T3;
    __shared__ float ts[32][33];
    const int k0 = blockIdx.y * 32, n0 = blockIdx.x * 32;
    const int r = threadIdx.x >> 3, c4 = (threadIdx.x & 7) * 4;
    float4 v = *(const float4*)&W[(size_t)(k0 + r) * 1024 + n0 + c4];
    ts[r][c4 + 0] = v.x; ts[r][c4 + 1] = v.y; ts[r][c4 + 2] = v.z; ts[r][c4 + 3] = v.w;
    __syncthreads();
    ushort4 o;
    o.x = f2b(ts[c4 + 0][r]); o.y = f2b(ts[c4 + 1][r]);
    o.z = f2b(ts[c4 + 2][r]); o.w = f2b(ts[c4 + 3][r]);
    *(ushort4*)&T[(size_t)(n0 + r) * 1024 + k0 + c4] = o;
}

// ---------------- MFMA bf16 GEMM body: C[.][1024] = A[.][1024] @ Bt^T + bias ----------------
// Bt is [N][K] bf16 (pre-transposed). A either fp32 (Af) or bf16 (Ab).
__device__ __forceinline__ void gemm_body(
    const float* Af, const ushort* Ab, const ushort* __restrict__ Bt,
    const float* __restrict__ bias, float* __restrict__ C, int m0, int n0)
{
    __shared__ ushort As[128 * 40];  // row stride 40 ushort = 20 words: frag reads 2-way free
    __shared__ ushort Bs[128 * 40];
    const int t = threadIdx.x;
    const int l = t & 63;
    const int w = t >> 6;
    const int wm = w >> 1, wn = w & 1;

    floatx4 acc[4][4] = {};

    const int r0 = t >> 2;        // 0..63
    const int c0 = t & 3;         // k-chunk (8 bf16)

    for (int k0 = 0; k0 < 1024; k0 += 32) {
        short8 a0, a1;
        if (Af) {
            const float* p0 = &Af[(size_t)(m0 + r0) * 1024 + k0 + c0 * 8];
            const float* p1 = &Af[(size_t)(m0 + r0 + 64) * 1024 + k0 + c0 * 8];
            float4 x0 = *(const float4*)p0, y0 = *(const float4*)(p0 + 4);
            float4 x1 = *(const float4*)p1, y1 = *(const float4*)(p1 + 4);
            a0[0] = (short)f2b(x0.x); a0[1] = (short)f2b(x0.y); a0[2] = (short)f2b(x0.z); a0[3] = (short)f2b(x0.w);
            a0[4] = (short)f2b(y0.x); a0[5] = (short)f2b(y0.y); a0[6] = (short)f2b(y0.z); a0[7] = (short)f2b(y0.w);
            a1[0] = (short)f2b(x1.x); a1[1] = (short)f2b(x1.y); a1[2] = (short)f2b(x1.z); a1[3] = (short)f2b(x1.w);
            a1[4] = (short)f2b(y1.x); a1[5] = (short)f2b(y1.y); a1[6] = (short)f2b(y1.z); a1[7] = (short)f2b(y1.w);
        } else {
            a0 = *(const short8*)&Ab[(size_t)(m0 + r0) * 1024 + k0 + c0 * 8];
            a1 = *(const short8*)&Ab[(size_t)(m0 + r0 + 64) * 1024 + k0 + c0 * 8];
        }
        short8 b0 = *(const short8*)&Bt[(size_t)(n0 + r0) * 1024 + k0 + c0 * 8];
        short8 b1 = *(const short8*)&Bt[(size_t)(n0 + r0 + 64) * 1024 + k0 + c0 * 8];

        __syncthreads();
        *(short8*)&As[r0 * 40 + c0 * 8] = a0;
        *(short8*)&As[(r0 + 64) * 40 + c0 * 8] = a1;
        *(short8*)&Bs[r0 * 40 + c0 * 8] = b0;
        *(short8*)&Bs[(r0 + 64) * 40 + c0 * 8] = b1;
        __syncthreads();

        short8 af[4], bf[4];
#pragma unroll
        for (int m = 0; m < 4; ++m)
            af[m] = *(const short8*)&As[(wm * 64 + m * 16 + (l & 15)) * 40 + (l >> 4) * 8];
#pragma unroll
        for (int n = 0; n < 4; ++n)
            bf[n] = *(const short8*)&Bs[(wn * 64 + n * 16 + (l & 15)) * 40 + (l >> 4) * 8];
#pragma unroll
        for (int m = 0; m < 4; ++m)
#pragma unroll
            for (int n = 0; n < 4; ++n)
                acc[m][n] = __builtin_amdgcn_mfma_f32_16x16x32_bf16(af[m], bf[n], acc[m][n], 0, 0, 0);
    }

    const int cr = (l >> 4) * 4;  // C row base within fragment
    const int cc = l & 15;        // C col within fragment
#pragma unroll
    for (int n = 0; n < 4; ++n) {
        int col = n0 + wn * 64 + n * 16 + cc;
        float bv = bias[col];
#pragma unroll
        for (int m = 0; m < 4; ++m) {
            int row = m0 + wm * 64 + m * 16 + cr;
#pragma unroll
            for (int j = 0; j < 4; ++j)
                C[(size_t)(row + j) * 1024 + col] = acc[m][n][j] + bv;
        }
    }
}

__global__ __launch_bounds__(256) void gemm_qkv(
    const float* __restrict__ Q, const float* __restrict__ K, const float* __restrict__ V,
    const ushort* __restrict__ Wqt, const ushort* __restrict__ Wkt, const ushort* __restrict__ Wvt,
    const float* __restrict__ bq, const float* __restrict__ bk, const float* __restrict__ bv,
    float* __restrict__ qp, float* __restrict__ kp, float* __restrict__ vp)
{
    const int z = blockIdx.z;
    const float* A = z == 0 ? Q : z == 1 ? K : V;
    const ushort* Bt = z == 0 ? Wqt : z == 1 ? Wkt : Wvt;
    const float* bias = z == 0 ? bq : z == 1 ? bk : bv;
    float* C = z == 0 ? qp : z == 1 ? kp : vp;
    gemm_body(A, nullptr, Bt, bias, C, blockIdx.y * 128, blockIdx.x * 128);
}

__global__ __launch_bounds__(256) void gemm_obf(
    const ushort* __restrict__ ctxb, const ushort* __restrict__ Wot,
    const float* __restrict__ bo, float* __restrict__ op)
{
    gemm_body(nullptr, ctxb, Wot, bo, op, blockIdx.y * 128, blockIdx.x * 128);
}

// ---------------- Banded attention (fp32 VALU): band-only writes, conflict-fixed ----------------
__global__ __launch_bounds__(256) void attn_kernel(
    const float* __restrict__ qp, const float* __restrict__ kp, const float* __restrict__ vp,
    float* __restrict__ attn, ushort* __restrict__ ctxb)
{
    __shared__ float qs[16][68];
    __shared__ float ks[64][68];
    __shared__ float sc[16][528];

    const int qb = blockIdx.x, h = blockIdx.y, b = blockIdx.z;
    const int i0 = qb * 16;
    const int jlo = max(0, i0 - (NW - 1));
    const int jhi = min(SS, i0 + 15 + NW);
    const int t = threadIdx.x;
    const int sr = t >> 4, g = t & 15;

    // q tile, pre-scaled by 1/sqrt(64)
    {
        int c = g * 4;
        float4 v = *(const float4*)&qp[(size_t)(b * SS + i0 + sr) * 1024 + h * 64 + c];
        qs[sr][c + 0] = v.x * 0.125f; qs[sr][c + 1] = v.y * 0.125f;
        qs[sr][c + 2] = v.z * 0.125f; qs[sr][c + 3] = v.w * 0.125f;
    }

    const int lrow = t >> 2, lc = (t & 3) * 4;

    // ---- scores over band ----
    for (int jt = jlo; jt < jhi; jt += 64) {
        __syncthreads();
        {
            int j = jt + lrow;
#pragma unroll
            for (int mm = 0; mm < 4; ++mm) {
                int c = lc + mm * 16;
                float4 v = make_float4(0.f, 0.f, 0.f, 0.f);
                if (j < jhi) v = *(const float4*)&kp[(size_t)(b * SS + j) * 1024 + h * 64 + c];
                *(float4*)&ks[lrow][c] = v;
            }
        }
        __syncthreads();
        float a[4] = {0.f, 0.f, 0.f, 0.f};
#pragma unroll
        for (int d = 0; d < 64; d += 4) {
            float4 q4 = *(const float4*)&qs[sr][d];
#pragma unroll
            for (int u = 0; u < 4; ++u) {
                float4 k4 = *(const float4*)&ks[g + 16 * u][d];  // rows g..g+48: 2-way, free
                a[u] += q4.x * k4.x + q4.y * k4.y + q4.z * k4.z + q4.w * k4.w;
            }
        }
        {
            int i = i0 + sr;
#pragma unroll
            for (int u = 0; u < 4; ++u) {
                int j = jt + g + 16 * u;
                if (j < jhi) {
                    int di = i - j; di = di < 0 ? -di : di;
                    sc[sr][j - jlo] = (di < NW) ? a[u] : -1e30f;
                }
            }
        }
    }
    __syncthreads();

    // ---- softmax per row (16 lanes per row) ----
    {
        const int width = jhi - jlo;
        float mx = -1e30f;
        for (int jj = g; jj < width; jj += 16) mx = fmaxf(mx, sc[sr][jj]);
#pragma unroll
        for (int off = 1; off < 16; off <<= 1) mx = fmaxf(mx, __shfl_xor(mx, off, 64));
        float sum = 0.f;
        for (int jj = g; jj < width; jj += 16) {
            float e = __expf(sc[sr][jj] - mx);
            sc[sr][jj] = e;
            sum += e;
        }
#pragma unroll
        for (int off = 1; off < 16; off <<= 1) sum += __shfl_xor(sum, off, 64);
        float inv = 1.0f / sum;
        for (int jj = g; jj < width; jj += 16) sc[sr][jj] *= inv;
    }
    __syncthreads();

    // ---- band-only attn writes (rest is memset zero) ----
    {
        const int jlo4 = jlo & ~3;
        float* arow = attn + (size_t)((b * HH + h) * SS + (i0 + sr)) * SS;
        for (int j4 = jlo4 + g * 4; j4 < jhi; j4 += 64) {
            float4 o;
            float* pe = &o.x;
#pragma unroll
            for (int e = 0; e < 4; ++e) {
                int j = j4 + e;
                pe[e] = (j >= jlo && j < jhi) ? sc[sr][j - jlo] : 0.f;
            }
            *(float4*)&arow[j4] = o;
        }
    }

    // ---- PV ----
    {
        const int dg = g * 4;
        float4 acc = make_float4(0.f, 0.f, 0.f, 0.f);
        for (int jt = jlo; jt < jhi; jt += 64) {
            __syncthreads();
            {
                int j = jt + lrow;
#pragma unroll
                for (int mm = 0; mm < 4; ++mm) {
                    int c = lc + mm * 16;
                    float4 v = make_float4(0.f, 0.f, 0.f, 0.f);
                    if (j < jhi) v = *(const float4*)&vp[(size_t)(b * SS + j) * 1024 + h * 64 + c];
                    *(float4*)&ks[lrow][c] = v;
                }
            }
            __syncthreads();
            const int lim = min(64, jhi - jt);
            const int base = jt - jlo;
#pragma unroll 4
            for (int u = 0; u < lim; ++u) {
                float p = sc[sr][base + u];
                float4 v4 = *(const float4*)&ks[u][dg];
                acc.x += p * v4.x; acc.y += p * v4.y;
                acc.z += p * v4.z; acc.w += p * v4.w;
            }
        }
        ushort4 o;
        o.x = f2b(acc.x); o.y = f2b(acc.y); o.z = f2b(acc.z); o.w = f2b(acc.w);
        *(ushort4*)&ctxb[(size_t)(b * SS + i0 + sr) * 1024 + h * 64 + dg] = o;
    }
}

// ---------------- residual + LayerNorm ----------------
__global__ __launch_bounds__(256) void ln_kernel(
    const float* __restrict__ op, const float* __restrict__ Qin,
    const float* __restrict__ gamma, const float* __restrict__ beta,
    float* __restrict__ y)
{
    const int row = blockIdx.x;
    const int t = threadIdx.x;
    __shared__ float rs[4], rss[4];

    float4 o4 = *(const float4*)&op[(size_t)row * 1024 + t * 4];
    float4 q4 = *(const float4*)&Qin[(size_t)row * 1024 + t * 4];
    float x0 = o4.x + q4.x, x1 = o4.y + q4.y, x2 = o4.z + q4.z, x3 = o4.w + q4.w;
    float s = x0 + x1 + x2 + x3;
    float ss = x0 * x0 + x1 * x1 + x2 * x2 + x3 * x3;
#pragma unroll
    for (int off = 1; off < 64; off <<= 1) {
        s  += __shfl_xor(s, off, 64);
        ss += __shfl_xor(ss, off, 64);
    }
    int wid = t >> 6;
    if ((t & 63) == 0) { rs[wid] = s; rss[wid] = ss; }
    __syncthreads();
    s  = rs[0] + rs[1] + rs[2] + rs[3];
    ss = rss[0] + rss[1] + rss[2] + rss[3];
    float mu = s * (1.0f / 1024.0f);
    float var = ss * (1.0f / 1024.0f) - mu * mu;
    float rstd = rsqrtf(var + LN_EPS);
    float4 g4 = *(const float4*)&gamma[t * 4];
    float4 b4 = *(const float4*)&beta[t * 4];
    float4 o;
    o.x = (x0 - mu) * rstd * g4.x + b4.x;
    o.y = (x1 - mu) * rstd * g4.y + b4.y;
    o.z = (x2 - mu) * rstd * g4.z + b4.z;
    o.w = (x3 - mu) * rstd * g4.w + b4.w;
    *(float4*)&y[(size_t)row * 1024 + t * 4] = o;
}

extern "C" void kernel_launch(void* const* d_in, const int* in_sizes, int n_in,
                              void* d_out, int out_size, void* d_ws, size_t ws_size,
                              hipStream_t stream) {
    (void)in_sizes; (void)n_in; (void)out_size; (void)ws_size;
    const float* Q  = (const float*)d_in[0];
    const float* K  = (const float*)d_in[1];
    const float* V  = (const float*)d_in[2];
    const float* Wq = (const float*)d_in[3];
    const float* bq = (const float*)d_in[4];
    const float* Wk = (const float*)d_in[5];
    const float* bk = (const float*)d_in[6];
    const float* Wv = (const float*)d_in[7];
    const float* bv = (const float*)d_in[8];
    const float* Wo = (const float*)d_in[9];
    const float* bo = (const float*)d_in[10];
    const float* gamma = (const float*)d_in[11];
    const float* beta  = (const float*)d_in[12];

    float* y = (float*)d_out;
    float* attn = y + (size_t)BB * SS * DD;  // 4,194,304 floats in

    float* ws = (float*)d_ws;
    float* qp = ws;                          // 4,194,304 f
    float* kp = ws + (size_t)4194304;
    float* vp = ws + (size_t)2 * 4194304;
    ushort* wsb = (ushort*)(ws + (size_t)3 * 4194304);
    ushort* Wqt = wsb;                       // 1,048,576 u16 each
    ushort* Wkt = wsb + (size_t)1048576;
    ushort* Wvt = wsb + (size_t)2097152;
    ushort* Wot = wsb + (size_t)3145728;
    ushort* ctxb = wsb + (size_t)4194304;    // 4,194,304 u16
    float* op = qp;                          // reuse after attention

    hipMemsetAsync(attn, 0, (size_t)BB * HH * SS * SS * 4, stream);
    wtrans<<<dim3(32, 32, 4), 256, 0, stream>>>(Wq, Wk, Wv, Wo, Wqt, Wkt, Wvt, Wot);
    gemm_qkv<<<dim3(8, 32, 3), 256, 0, stream>>>(Q, K, V, Wqt, Wkt, Wvt, bq, bk, bv, qp, kp, vp);
    attn_kernel<<<dim3(SS / 16, HH, BB), 256, 0, stream>>>(qp, kp, vp, attn, ctxb);
    gemm_obf<<<dim3(8, 32), 256, 0, stream>>>(ctxb, Wot, bo, op);
    ln_kernel<<<4096, 256, 0, stream>>>(op, Q, gamma, beta, y);
}

// Round 4
// 294.630 us; speedup vs baseline: 4.3906x; 2.7471x over previous
//
#include <hip/hip_runtime.h>
#include <hip/hip_bf16.h>

#define BB 2
#define SS 2048
#define HH 16
#define LN_EPS 1e-5f
#define LOG2E 1.44269504088896f

typedef __attribute__((ext_vector_type(8))) short short8;
typedef __attribute__((ext_vector_type(4))) float floatx4;

#define EXP2F(x) __builtin_amdgcn_exp2f(x)

__device__ __forceinline__ ushort f2b(float f) {
    union { float f; unsigned u; } x; x.f = f;
    unsigned u = x.u;
    return (ushort)((u + 0x7FFFu + ((u >> 16) & 1u)) >> 16);
}
__device__ __forceinline__ float b2f(ushort u) {
    union { unsigned u; float f; } x; x.u = ((unsigned)u) << 16;
    return x.f;
}

// ---------------- W transpose+convert: T[n][k] = bf16(scale*W[k][n]) ----------------
__global__ __launch_bounds__(256) void wtrans(
    const float* __restrict__ W0, const float* __restrict__ W1,
    const float* __restrict__ W2, const float* __restrict__ W3,
    ushort* __restrict__ T0, ushort* __restrict__ T1,
    ushort* __restrict__ T2, ushort* __restrict__ T3)
{
    const int z = blockIdx.z;
    const float* W = z == 0 ? W0 : z == 1 ? W1 : z == 2 ? W2 : W3;
    ushort* T = z == 0 ? T0 : z == 1 ? T1 : z == 2 ? T2 : T3;
    const float scale = (z == 0) ? 0.125f : 1.0f;  // fold 1/sqrt(DK) into Wq
    __shared__ float ts[32][33];
    const int k0 = blockIdx.y * 32, n0 = blockIdx.x * 32;
    const int r = threadIdx.x >> 3, c4 = (threadIdx.x & 7) * 4;
    float4 v = *(const float4*)&W[(size_t)(k0 + r) * 1024 + n0 + c4];
    ts[r][c4 + 0] = v.x; ts[r][c4 + 1] = v.y; ts[r][c4 + 2] = v.z; ts[r][c4 + 3] = v.w;
    __syncthreads();
    ushort4 o;
    o.x = f2b(ts[c4 + 0][r] * scale); o.y = f2b(ts[c4 + 1][r] * scale);
    o.z = f2b(ts[c4 + 2][r] * scale); o.w = f2b(ts[c4 + 3][r] * scale);
    *(ushort4*)&T[(size_t)(n0 + r) * 1024 + k0 + c4] = o;
}

// ---------------- MFMA bf16 GEMM body ----------------
__device__ __forceinline__ void gemm_body(
    const float* Af, const ushort* Ab, const ushort* __restrict__ Bt,
    const float* __restrict__ bias, float bscale,
    float* Cf, ushort* Cb, int m0, int n0)
{
    __shared__ ushort As[128 * 40];
    __shared__ ushort Bs[128 * 40];
    const int t = threadIdx.x;
    const int l = t & 63;
    const int w = t >> 6;
    const int wm = w >> 1, wn = w & 1;

    floatx4 acc[4][4] = {};
    const int r0 = t >> 2;
    const int c0 = t & 3;

    for (int k0 = 0; k0 < 1024; k0 += 32) {
        short8 a0, a1;
        if (Af) {
            const float* p0 = &Af[(size_t)(m0 + r0) * 1024 + k0 + c0 * 8];
            const float* p1 = &Af[(size_t)(m0 + r0 + 64) * 1024 + k0 + c0 * 8];
            float4 x0 = *(const float4*)p0, y0 = *(const float4*)(p0 + 4);
            float4 x1 = *(const float4*)p1, y1 = *(const float4*)(p1 + 4);
            a0[0] = (short)f2b(x0.x); a0[1] = (short)f2b(x0.y); a0[2] = (short)f2b(x0.z); a0[3] = (short)f2b(x0.w);
            a0[4] = (short)f2b(y0.x); a0[5] = (short)f2b(y0.y); a0[6] = (short)f2b(y0.z); a0[7] = (short)f2b(y0.w);
            a1[0] = (short)f2b(x1.x); a1[1] = (short)f2b(x1.y); a1[2] = (short)f2b(x1.z); a1[3] = (short)f2b(x1.w);
            a1[4] = (short)f2b(y1.x); a1[5] = (short)f2b(y1.y); a1[6] = (short)f2b(y1.z); a1[7] = (short)f2b(y1.w);
        } else {
            a0 = *(const short8*)&Ab[(size_t)(m0 + r0) * 1024 + k0 + c0 * 8];
            a1 = *(const short8*)&Ab[(size_t)(m0 + r0 + 64) * 1024 + k0 + c0 * 8];
        }
        short8 b0 = *(const short8*)&Bt[(size_t)(n0 + r0) * 1024 + k0 + c0 * 8];
        short8 b1 = *(const short8*)&Bt[(size_t)(n0 + r0 + 64) * 1024 + k0 + c0 * 8];

        __syncthreads();
        *(short8*)&As[r0 * 40 + c0 * 8] = a0;
        *(short8*)&As[(r0 + 64) * 40 + c0 * 8] = a1;
        *(short8*)&Bs[r0 * 40 + c0 * 8] = b0;
        *(short8*)&Bs[(r0 + 64) * 40 + c0 * 8] = b1;
        __syncthreads();

        short8 af[4], bf[4];
#pragma unroll
        for (int m = 0; m < 4; ++m)
            af[m] = *(const short8*)&As[(wm * 64 + m * 16 + (l & 15)) * 40 + (l >> 4) * 8];
#pragma unroll
        for (int n = 0; n < 4; ++n)
            bf[n] = *(const short8*)&Bs[(wn * 64 + n * 16 + (l & 15)) * 40 + (l >> 4) * 8];
#pragma unroll
        for (int m = 0; m < 4; ++m)
#pragma unroll
            for (int n = 0; n < 4; ++n)
                acc[m][n] = __builtin_amdgcn_mfma_f32_16x16x32_bf16(af[m], bf[n], acc[m][n], 0, 0, 0);
    }

    const int cr = (l >> 4) * 4;
    const int cc = l & 15;
#pragma unroll
    for (int n = 0; n < 4; ++n) {
        int col = n0 + wn * 64 + n * 16 + cc;
        float bv = bias[col] * bscale;
#pragma unroll
        for (int m = 0; m < 4; ++m) {
            int row = m0 + wm * 64 + m * 16 + cr;
#pragma unroll
            for (int j = 0; j < 4; ++j) {
                float v = acc[m][n][j] + bv;
                if (Cf) Cf[(size_t)(row + j) * 1024 + col] = v;
                else    Cb[(size_t)(row + j) * 1024 + col] = f2b(v);
            }
        }
    }
}

__global__ __launch_bounds__(256) void gemm_qkv(
    const float* __restrict__ Q, const float* __restrict__ K, const float* __restrict__ V,
    const ushort* __restrict__ Wqt, const ushort* __restrict__ Wkt, const ushort* __restrict__ Wvt,
    const float* __restrict__ bq, const float* __restrict__ bk, const float* __restrict__ bv,
    ushort* __restrict__ qp, ushort* __restrict__ kp, ushort* __restrict__ vp)
{
    const int z = blockIdx.z;
    const float* A = z == 0 ? Q : z == 1 ? K : V;
    const ushort* Bt = z == 0 ? Wqt : z == 1 ? Wkt : Wvt;
    const float* bias = z == 0 ? bq : z == 1 ? bk : bv;
    ushort* C = z == 0 ? qp : z == 1 ? kp : vp;
    float bscale = (z == 0) ? 0.125f : 1.0f;
    gemm_body(A, nullptr, Bt, bias, bscale, nullptr, C, blockIdx.y * 128, blockIdx.x * 128);
}

__global__ __launch_bounds__(256) void gemm_obf(
    const ushort* __restrict__ ctxb, const ushort* __restrict__ Wot,
    const float* __restrict__ bo, float* __restrict__ op)
{
    gemm_body(nullptr, ctxb, Wot, bo, 1.0f, op, nullptr, blockIdx.y * 128, blockIdx.x * 128);
}

// ---------------- MFMA banded attention: 64 q-rows/block, 4 waves x 16 rows ----------------
__global__ __launch_bounds__(256) void attn_mfma(
    const ushort* __restrict__ qb, const ushort* __restrict__ kb, const ushort* __restrict__ vb,
    float* __restrict__ attn, ushort* __restrict__ ctxb)
{
    __shared__ alignas(16) ushort Ks[64 * 72];
    __shared__ alignas(16) ushort Vt[64 * 72];
    __shared__ alignas(16) ushort Pl[4][16 * 72];

    const int qblk = blockIdx.x, h = blockIdx.y, b = blockIdx.z;
    const int i0 = qblk * 64;
    const int t = threadIdx.x;
    const int w = t >> 6, l = t & 63;
    const int g = l >> 4, c = l & 15;
    const int ibase = i0 + w * 16;

    const int jstart = max(0, i0 - 256);            // 64-aligned
    const int jend = min(SS, i0 + 64 + 256);        // 64-aligned

    // Q A-fragments (rows ibase..ibase+15, pre-scaled via Wq)
    const size_t qoff = (size_t)(b * SS + ibase + c) * 1024 + h * 64 + g * 8;
    short8 aq0 = *(const short8*)&qb[qoff];
    short8 aq1 = *(const short8*)&qb[qoff + 32];

    const int krow = t >> 2, kd0 = (t & 3) * 16;
    const int vj0 = (t & 31) * 2, vd0 = (t >> 5) * 8;

    float m[4] = {-3e38f, -3e38f, -3e38f, -3e38f};
    float ll[4] = {0.f, 0.f, 0.f, 0.f};

    // ---- pass 1: running row max + sum (exp2 domain), in registers ----
    for (int jt = jstart; jt < jend; jt += 64) {
        __syncthreads();
        {
            const ushort* kr = &kb[(size_t)(b * SS + jt + krow) * 1024 + h * 64 + kd0];
            short8 k0 = *(const short8*)kr;
            short8 k1 = *(const short8*)(kr + 8);
            *(short8*)&Ks[krow * 72 + kd0] = k0;
            *(short8*)&Ks[krow * 72 + kd0 + 8] = k1;
        }
        __syncthreads();
        floatx4 s[4] = {};
#pragma unroll
        for (int u = 0; u < 4; ++u) {
            short8 b0 = *(const short8*)&Ks[(u * 16 + c) * 72 + g * 8];
            short8 b1 = *(const short8*)&Ks[(u * 16 + c) * 72 + 32 + g * 8];
            s[u] = __builtin_amdgcn_mfma_f32_16x16x32_bf16(aq0, b0, s[u], 0, 0, 0);
            s[u] = __builtin_amdgcn_mfma_f32_16x16x32_bf16(aq1, b1, s[u], 0, 0, 0);
        }
        const bool full = (jt >= ibase - 240) && (jt <= ibase + 192);
#pragma unroll
        for (int r = 0; r < 4; ++r) {
            float v0 = s[0][r] * LOG2E, v1 = s[1][r] * LOG2E,
                  v2 = s[2][r] * LOG2E, v3 = s[3][r] * LOG2E;
            if (!full) {
                const int i = ibase + g * 4 + r;
                const int j0 = jt + c;
                if ((unsigned)(i - j0 + 255) >= 511u)        v0 = -3e38f;
                if ((unsigned)(i - (j0 + 16) + 255) >= 511u) v1 = -3e38f;
                if ((unsigned)(i - (j0 + 32) + 255) >= 511u) v2 = -3e38f;
                if ((unsigned)(i - (j0 + 48) + 255) >= 511u) v3 = -3e38f;
            }
            float tmax = fmaxf(fmaxf(v0, v1), fmaxf(v2, v3));
            float mn = fmaxf(m[r], tmax);
            float sc_ = EXP2F(m[r] - mn);
            float add = EXP2F(v0 - mn) + EXP2F(v1 - mn)
                      + EXP2F(v2 - mn) + EXP2F(v3 - mn);
            ll[r] = ll[r] * sc_ + add;
            m[r] = mn;
        }
    }

    // ---- finalize softmax stats across the 16 j-lanes of each row ----
    float M[4], invL[4];
#pragma unroll
    for (int r = 0; r < 4; ++r) {
        float mm = m[r];
        mm = fmaxf(mm, __shfl_xor(mm, 1));
        mm = fmaxf(mm, __shfl_xor(mm, 2));
        mm = fmaxf(mm, __shfl_xor(mm, 4));
        mm = fmaxf(mm, __shfl_xor(mm, 8));
        float la = ll[r] * EXP2F(m[r] - mm);
        la += __shfl_xor(la, 1);
        la += __shfl_xor(la, 2);
        la += __shfl_xor(la, 4);
        la += __shfl_xor(la, 8);
        M[r] = mm;
        invL[r] = 1.0f / la;
    }

    // ---- pass 2: probs -> attn + PV ----
    floatx4 ctx[4] = {};
    for (int jt = jstart; jt < jend; jt += 64) {
        __syncthreads();
        {
            const ushort* kr = &kb[(size_t)(b * SS + jt + krow) * 1024 + h * 64 + kd0];
            short8 k0 = *(const short8*)kr;
            short8 k1 = *(const short8*)(kr + 8);
            *(short8*)&Ks[krow * 72 + kd0] = k0;
            *(short8*)&Ks[krow * 72 + kd0 + 8] = k1;
        }
        {
            const ushort* vr = &vb[(size_t)(b * SS + jt + vj0) * 1024 + h * 64 + vd0];
            short8 v0 = *(const short8*)vr;
            short8 v1 = *(const short8*)(vr + 1024);
#pragma unroll
            for (int e = 0; e < 8; ++e) {
                ushort2 pr;
                pr.x = (ushort)v0[e];
                pr.y = (ushort)v1[e];
                *(ushort2*)&Vt[(vd0 + e) * 72 + vj0] = pr;
            }
        }
        __syncthreads();
        floatx4 s[4] = {};
#pragma unroll
        for (int u = 0; u < 4; ++u) {
            short8 b0 = *(const short8*)&Ks[(u * 16 + c) * 72 + g * 8];
            short8 b1 = *(const short8*)&Ks[(u * 16 + c) * 72 + 32 + g * 8];
            s[u] = __builtin_amdgcn_mfma_f32_16x16x32_bf16(aq0, b0, s[u], 0, 0, 0);
            s[u] = __builtin_amdgcn_mfma_f32_16x16x32_bf16(aq1, b1, s[u], 0, 0, 0);
        }
        const bool full = (jt >= ibase - 240) && (jt <= ibase + 192);
#pragma unroll
        for (int u = 0; u < 4; ++u) {
#pragma unroll
            for (int r = 0; r < 4; ++r) {
                float v = s[u][r] * LOG2E;
                if (!full) {
                    const int i = ibase + g * 4 + r;
                    const int j = jt + u * 16 + c;
                    if ((unsigned)(i - j + 255) >= 511u) v = -3e38f;
                }
                float p = EXP2F(v - M[r]) * invL[r];
                Pl[w][(g * 4 + r) * 72 + u * 16 + c] = f2b(p);
            }
        }
        // write attn band tile (256B contiguous per row-quarter)
#pragma unroll
        for (int it = 0; it < 4; ++it) {
            const int row = it * 4 + g;
            ushort4 pw = *(const ushort4*)&Pl[w][row * 72 + c * 4];
            float4 o;
            o.x = b2f(pw.x); o.y = b2f(pw.y); o.z = b2f(pw.z); o.w = b2f(pw.w);
            *(float4*)&attn[(size_t)(b * HH + h) * SS * SS + (size_t)(ibase + row) * SS + jt + c * 4] = o;
        }
        // PV: ctx += P @ V
#pragma unroll
        for (int jc = 0; jc < 2; ++jc) {
            short8 pa = *(const short8*)&Pl[w][c * 72 + jc * 32 + g * 8];
#pragma unroll
            for (int ds = 0; ds < 4; ++ds) {
                short8 bv_ = *(const short8*)&Vt[(ds * 16 + c) * 72 + jc * 32 + g * 8];
                ctx[ds] = __builtin_amdgcn_mfma_f32_16x16x32_bf16(pa, bv_, ctx[ds], 0, 0, 0);
            }
        }
    }

    // ---- ctx out (bf16) ----
#pragma unroll
    for (int ds = 0; ds < 4; ++ds)
#pragma unroll
        for (int r = 0; r < 4; ++r)
            ctxb[(size_t)(b * SS + ibase + g * 4 + r) * 1024 + h * 64 + ds * 16 + c] = f2b(ctx[ds][r]);

    // ---- zero-fill attn outside [jstart, jend) (at end: no barrier drains these stores) ----
    {
        float* ab = attn + (size_t)(b * HH + h) * SS * SS;
        const float4 z4 = make_float4(0.f, 0.f, 0.f, 0.f);
        const int g16 = t >> 4, c16 = t & 15;
#pragma unroll
        for (int rr = 0; rr < 4; ++rr) {
            float* rp = ab + (size_t)(i0 + g16 + rr * 16) * SS;
            for (int x = c16 * 4; x < jstart; x += 64) *(float4*)&rp[x] = z4;
            for (int x = jend + c16 * 4; x < SS; x += 64) *(float4*)&rp[x] = z4;
        }
    }
}

// ---------------- residual + LayerNorm ----------------
__global__ __launch_bounds__(256) void ln_kernel(
    const float* __restrict__ op, const float* __restrict__ Qin,
    const float* __restrict__ gamma, const float* __restrict__ beta,
    float* __restrict__ y)
{
    const int row = blockIdx.x;
    const int t = threadIdx.x;
    __shared__ float rs[4], rss[4];

    float4 o4 = *(const float4*)&op[(size_t)row * 1024 + t * 4];
    float4 q4 = *(const float4*)&Qin[(size_t)row * 1024 + t * 4];
    float x0 = o4.x + q4.x, x1 = o4.y + q4.y, x2 = o4.z + q4.z, x3 = o4.w + q4.w;
    float s = x0 + x1 + x2 + x3;
    float ss = x0 * x0 + x1 * x1 + x2 * x2 + x3 * x3;
#pragma unroll
    for (int off = 1; off < 64; off <<= 1) {
        s  += __shfl_xor(s, off, 64);
        ss += __shfl_xor(ss, off, 64);
    }
    int wid = t >> 6;
    if ((t & 63) == 0) { rs[wid] = s; rss[wid] = ss; }
    __syncthreads();
    s  = rs[0] + rs[1] + rs[2] + rs[3];
    ss = rss[0] + rss[1] + rss[2] + rss[3];
    float mu = s * (1.0f / 1024.0f);
    float var = ss * (1.0f / 1024.0f) - mu * mu;
    float rstd = rsqrtf(var + LN_EPS);
    float4 g4 = *(const float4*)&gamma[t * 4];
    float4 b4 = *(const float4*)&beta[t * 4];
    float4 o;
    o.x = (x0 - mu) * rstd * g4.x + b4.x;
    o.y = (x1 - mu) * rstd * g4.y + b4.y;
    o.z = (x2 - mu) * rstd * g4.z + b4.z;
    o.w = (x3 - mu) * rstd * g4.w + b4.w;
    *(float4*)&y[(size_t)row * 1024 + t * 4] = o;
}

extern "C" void kernel_launch(void* const* d_in, const int* in_sizes, int n_in,
                              void* d_out, int out_size, void* d_ws, size_t ws_size,
                              hipStream_t stream) {
    (void)in_sizes; (void)n_in; (void)out_size; (void)ws_size;
    const float* Q  = (const float*)d_in[0];
    const float* K  = (const float*)d_in[1];
    const float* V  = (const float*)d_in[2];
    const float* Wq = (const float*)d_in[3];
    const float* bq = (const float*)d_in[4];
    const float* Wk = (const float*)d_in[5];
    const float* bk = (const float*)d_in[6];
    const float* Wv = (const float*)d_in[7];
    const float* bv = (const float*)d_in[8];
    const float* Wo = (const float*)d_in[9];
    const float* bo = (const float*)d_in[10];
    const float* gamma = (const float*)d_in[11];
    const float* beta  = (const float*)d_in[12];

    float* y = (float*)d_out;
    float* attn = y + (size_t)BB * SS * 1024;

    float* op = (float*)d_ws;                       // 4,194,304 floats
    ushort* ub = (ushort*)(op + 4194304);
    ushort* qbp  = ub;                              // 4,194,304 u16 each
    ushort* kbp  = ub + (size_t)4194304;
    ushort* vbp  = ub + (size_t)2 * 4194304;
    ushort* ctxb = ub + (size_t)3 * 4194304;
    ushort* Wqt  = ub + (size_t)4 * 4194304;        // 1,048,576 u16 each
    ushort* Wkt  = Wqt + 1048576;
    ushort* Wvt  = Wkt + 1048576;
    ushort* Wot  = Wvt + 1048576;

    wtrans<<<dim3(32, 32, 4), 256, 0, stream>>>(Wq, Wk, Wv, Wo, Wqt, Wkt, Wvt, Wot);
    gemm_qkv<<<dim3(8, 32, 3), 256, 0, stream>>>(Q, K, V, Wqt, Wkt, Wvt, bq, bk, bv, qbp, kbp, vbp);
    attn_mfma<<<dim3(SS / 64, HH, BB), 256, 0, stream>>>(qbp, kbp, vbp, attn, ctxb);
    gemm_obf<<<dim3(8, 32), 256, 0, stream>>>(ctxb, Wot, bo, op);
    ln_kernel<<<4096, 256, 0, stream>>>(op, Q, gamma, beta, y);
}

// Round 6
// 239.494 us; speedup vs baseline: 5.4014x; 1.2302x over previous
//
#include <hip/hip_runtime.h>
#include <hip/hip_bf16.h>

#define BB 2
#define SS 2048
#define HH 16
#define LN_EPS 1e-5f
#define LOG2E 1.44269504088896f

typedef __attribute__((ext_vector_type(8))) short short8;
typedef __attribute__((ext_vector_type(4))) float floatx4;

#define EXP2F(x) __builtin_amdgcn_exp2f(x)

__device__ __forceinline__ ushort f2b(float f) {
    union { float f; unsigned u; } x; x.f = f;
    unsigned u = x.u;
    return (ushort)((u + 0x7FFFu + ((u >> 16) & 1u)) >> 16);
}
__device__ __forceinline__ float b2f(ushort u) {
    union { unsigned u; float f; } x; x.u = ((unsigned)u) << 16;
    return x.f;
}

// ---------------- W transpose+convert: T[n][k] = bf16(scale*W[k][n]) ----------------
__global__ __launch_bounds__(256) void wtrans(
    const float* __restrict__ W0, const float* __restrict__ W1,
    const float* __restrict__ W2, const float* __restrict__ W3,
    ushort* __restrict__ T0, ushort* __restrict__ T1,
    ushort* __restrict__ T2, ushort* __restrict__ T3)
{
    const int z = blockIdx.z;
    const float* W = z == 0 ? W0 : z == 1 ? W1 : z == 2 ? W2 : W3;
    ushort* T = z == 0 ? T0 : z == 1 ? T1 : z == 2 ? T2 : T3;
    const float scale = (z == 0) ? 0.125f : 1.0f;  // fold 1/sqrt(DK) into Wq
    __shared__ float ts[32][33];
    const int k0 = blockIdx.y * 32, n0 = blockIdx.x * 32;
    const int r = threadIdx.x >> 3, c4 = (threadIdx.x & 7) * 4;
    float4 v = *(const float4*)&W[(size_t)(k0 + r) * 1024 + n0 + c4];
    ts[r][c4 + 0] = v.x; ts[r][c4 + 1] = v.y; ts[r][c4 + 2] = v.z; ts[r][c4 + 3] = v.w;
    __syncthreads();
    ushort4 o;
    o.x = f2b(ts[c4 + 0][r] * scale); o.y = f2b(ts[c4 + 1][r] * scale);
    o.z = f2b(ts[c4 + 2][r] * scale); o.w = f2b(ts[c4 + 3][r] * scale);
    *(ushort4*)&T[(size_t)(n0 + r) * 1024 + k0 + c4] = o;
}

// ---------------- MFMA bf16 GEMM body: 128x64 tile, 4 waves (2x2), acc 4x2 ----------------
__device__ __forceinline__ void gemm_body(
    const float* Af, const ushort* Ab, const ushort* __restrict__ Bt,
    const float* __restrict__ bias, float bscale,
    float* Cf, ushort* Cb, int m0, int n0)
{
    __shared__ ushort As[128 * 40];
    __shared__ ushort Bs[64 * 40];
    const int t = threadIdx.x;
    const int l = t & 63;
    const int w = t >> 6;
    const int wm = w >> 1, wn = w & 1;

    floatx4 acc[4][2] = {};
    const int r0 = t >> 2;        // 0..63
    const int c0 = t & 3;         // 16B chunk

    for (int k0 = 0; k0 < 1024; k0 += 32) {
        short8 a0, a1;
        if (Af) {
            const float* p0 = &Af[(size_t)(m0 + r0) * 1024 + k0 + c0 * 8];
            const float* p1 = &Af[(size_t)(m0 + r0 + 64) * 1024 + k0 + c0 * 8];
            float4 x0 = *(const float4*)p0, y0 = *(const float4*)(p0 + 4);
            float4 x1 = *(const float4*)p1, y1 = *(const float4*)(p1 + 4);
            a0[0] = (short)f2b(x0.x); a0[1] = (short)f2b(x0.y); a0[2] = (short)f2b(x0.z); a0[3] = (short)f2b(x0.w);
            a0[4] = (short)f2b(y0.x); a0[5] = (short)f2b(y0.y); a0[6] = (short)f2b(y0.z); a0[7] = (short)f2b(y0.w);
            a1[0] = (short)f2b(x1.x); a1[1] = (short)f2b(x1.y); a1[2] = (short)f2b(x1.z); a1[3] = (short)f2b(x1.w);
            a1[4] = (short)f2b(y1.x); a1[5] = (short)f2b(y1.y); a1[6] = (short)f2b(y1.z); a1[7] = (short)f2b(y1.w);
        } else {
            a0 = *(const short8*)&Ab[(size_t)(m0 + r0) * 1024 + k0 + c0 * 8];
            a1 = *(const short8*)&Ab[(size_t)(m0 + r0 + 64) * 1024 + k0 + c0 * 8];
        }
        short8 b0 = *(const short8*)&Bt[(size_t)(n0 + r0) * 1024 + k0 + c0 * 8];

        __syncthreads();
        *(short8*)&As[r0 * 40 + c0 * 8] = a0;
        *(short8*)&As[(r0 + 64) * 40 + c0 * 8] = a1;
        *(short8*)&Bs[r0 * 40 + c0 * 8] = b0;
        __syncthreads();

        short8 af[4], bf[2];
#pragma unroll
        for (int m = 0; m < 4; ++m)
            af[m] = *(const short8*)&As[(wm * 64 + m * 16 + (l & 15)) * 40 + (l >> 4) * 8];
#pragma unroll
        for (int n = 0; n < 2; ++n)
            bf[n] = *(const short8*)&Bs[(wn * 32 + n * 16 + (l & 15)) * 40 + (l >> 4) * 8];
#pragma unroll
        for (int m = 0; m < 4; ++m)
#pragma unroll
            for (int n = 0; n < 2; ++n)
                acc[m][n] = __builtin_amdgcn_mfma_f32_16x16x32_bf16(af[m], bf[n], acc[m][n], 0, 0, 0);
    }

    const int cr = (l >> 4) * 4;
    const int cc = l & 15;
#pragma unroll
    for (int n = 0; n < 2; ++n) {
        int col = n0 + wn * 32 + n * 16 + cc;
        float bv = bias[col] * bscale;
#pragma unroll
        for (int m = 0; m < 4; ++m) {
            int row = m0 + wm * 64 + m * 16 + cr;
#pragma unroll
            for (int j = 0; j < 4; ++j) {
                float v = acc[m][n][j] + bv;
                if (Cf) Cf[(size_t)(row + j) * 1024 + col] = v;
                else    Cb[(size_t)(row + j) * 1024 + col] = f2b(v);
            }
        }
    }
}

// XCD-aware swizzle: 512 blocks -> each XCD owns a contiguous 4-panel m-range
// (2MB fp32 A panel fits its private L2) x all 16 n-tiles.
__device__ __forceinline__ void swz_mn(int& m0, int& n0) {
    int bid = blockIdx.x + (blockIdx.y << 4);   // 0..511
    int xcd = bid & 7, idx = bid >> 3;          // 64 blocks per xcd
    m0 = (xcd * 4 + (idx & 3)) * 128;
    n0 = (idx >> 2) * 64;
}

__global__ __launch_bounds__(256) void gemm_qkv(
    const float* __restrict__ Q, const float* __restrict__ K, const float* __restrict__ V,
    const ushort* __restrict__ Wqt, const ushort* __restrict__ Wkt, const ushort* __restrict__ Wvt,
    const float* __restrict__ bq, const float* __restrict__ bk, const float* __restrict__ bv,
    ushort* __restrict__ qp, ushort* __restrict__ kp, ushort* __restrict__ vp)
{
    const int z = blockIdx.z;
    const float* A = z == 0 ? Q : z == 1 ? K : V;
    const ushort* Bt = z == 0 ? Wqt : z == 1 ? Wkt : Wvt;
    const float* bias = z == 0 ? bq : z == 1 ? bk : bv;
    ushort* C = z == 0 ? qp : z == 1 ? kp : vp;
    float bscale = (z == 0) ? 0.125f : 1.0f;
    int m0, n0; swz_mn(m0, n0);
    gemm_body(A, nullptr, Bt, bias, bscale, nullptr, C, m0, n0);
}

__global__ __launch_bounds__(256) void gemm_obf(
    const ushort* __restrict__ ctxb, const ushort* __restrict__ Wot,
    const float* __restrict__ bo, float* __restrict__ op)
{
    int m0, n0; swz_mn(m0, n0);
    gemm_body(nullptr, ctxb, Wot, bo, 1.0f, op, nullptr, m0, n0);
}

// ---------------- MFMA banded attention: 64 q-rows/block, 4 waves x 16 rows ----------------
__global__ __launch_bounds__(256, 4) void attn_mfma(
    const ushort* __restrict__ qb, const ushort* __restrict__ kb, const ushort* __restrict__ vb,
    float* __restrict__ attn, ushort* __restrict__ ctxb)
{
    __shared__ alignas(16) ushort Ks[64 * 72];
    __shared__ alignas(16) ushort Vt[64 * 72];
    __shared__ alignas(16) ushort Pl[4][16 * 72];

    const int qblk = blockIdx.x, h = blockIdx.y, b = blockIdx.z;
    const int i0 = qblk * 64;
    const int t = threadIdx.x;
    const int w = t >> 6, l = t & 63;
    const int g = l >> 4, c = l & 15;
    const int ibase = i0 + w * 16;

    const int jstart = max(0, i0 - 256);            // 64-aligned
    const int jend = min(SS, i0 + 64 + 256);        // 64-aligned

    // Q A-fragments (rows ibase..ibase+15, pre-scaled via Wq)
    const size_t qoff = (size_t)(b * SS + ibase + c) * 1024 + h * 64 + g * 8;
    short8 aq0 = *(const short8*)&qb[qoff];
    short8 aq1 = *(const short8*)&qb[qoff + 32];

    const int krow = t >> 2, kd0 = (t & 3) * 16;
    const int vj0 = (t & 31) * 2, vd0 = (t >> 5) * 8;

    float m[4] = {-3e38f, -3e38f, -3e38f, -3e38f};
    float ll[4] = {0.f, 0.f, 0.f, 0.f};

    // ---- pass 1: running row max + sum (exp2 domain), in registers ----
    for (int jt = jstart; jt < jend; jt += 64) {
        __syncthreads();
        {
            const ushort* kr = &kb[(size_t)(b * SS + jt + krow) * 1024 + h * 64 + kd0];
            short8 k0 = *(const short8*)kr;
            short8 k1 = *(const short8*)(kr + 8);
            *(short8*)&Ks[krow * 72 + kd0] = k0;
            *(short8*)&Ks[krow * 72 + kd0 + 8] = k1;
        }
        __syncthreads();
        floatx4 s[4] = {};
#pragma unroll
        for (int u = 0; u < 4; ++u) {
            short8 b0 = *(const short8*)&Ks[(u * 16 + c) * 72 + g * 8];
            short8 b1 = *(const short8*)&Ks[(u * 16 + c) * 72 + 32 + g * 8];
            s[u] = __builtin_amdgcn_mfma_f32_16x16x32_bf16(aq0, b0, s[u], 0, 0, 0);
            s[u] = __builtin_amdgcn_mfma_f32_16x16x32_bf16(aq1, b1, s[u], 0, 0, 0);
        }
        const bool full = (jt >= ibase - 240) && (jt <= ibase + 192);
#pragma unroll
        for (int r = 0; r < 4; ++r) {
            float v0 = s[0][r] * LOG2E, v1 = s[1][r] * LOG2E,
                  v2 = s[2][r] * LOG2E, v3 = s[3][r] * LOG2E;
            if (!full) {
                const int i = ibase + g * 4 + r;
                const int j0 = jt + c;
                if ((unsigned)(i - j0 + 255) >= 511u)        v0 = -3e38f;
                if ((unsigned)(i - (j0 + 16) + 255) >= 511u) v1 = -3e38f;
                if ((unsigned)(i - (j0 + 32) + 255) >= 511u) v2 = -3e38f;
                if ((unsigned)(i - (j0 + 48) + 255) >= 511u) v3 = -3e38f;
            }
            float tmax = fmaxf(fmaxf(v0, v1), fmaxf(v2, v3));
            float mn = fmaxf(m[r], tmax);
            float sc_ = EXP2F(m[r] - mn);
            float add = EXP2F(v0 - mn) + EXP2F(v1 - mn)
                      + EXP2F(v2 - mn) + EXP2F(v3 - mn);
            ll[r] = ll[r] * sc_ + add;
            m[r] = mn;
        }
    }

    // ---- finalize softmax stats across the 16 j-lanes of each row ----
    float M[4], invL[4];
#pragma unroll
    for (int r = 0; r < 4; ++r) {
        float mm = m[r];
        mm = fmaxf(mm, __shfl_xor(mm, 1));
        mm = fmaxf(mm, __shfl_xor(mm, 2));
        mm = fmaxf(mm, __shfl_xor(mm, 4));
        mm = fmaxf(mm, __shfl_xor(mm, 8));
        float la = ll[r] * EXP2F(m[r] - mm);
        la += __shfl_xor(la, 1);
        la += __shfl_xor(la, 2);
        la += __shfl_xor(la, 4);
        la += __shfl_xor(la, 8);
        M[r] = mm;
        invL[r] = 1.0f / la;
    }

    // ---- pass 2: probs -> attn + PV ----
    floatx4 ctx[4] = {};
    for (int jt = jstart; jt < jend; jt += 64) {
        __syncthreads();
        {
            const ushort* kr = &kb[(size_t)(b * SS + jt + krow) * 1024 + h * 64 + kd0];
            short8 k0 = *(const short8*)kr;
            short8 k1 = *(const short8*)(kr + 8);
            *(short8*)&Ks[krow * 72 + kd0] = k0;
            *(short8*)&Ks[krow * 72 + kd0 + 8] = k1;
        }
        {
            const ushort* vr = &vb[(size_t)(b * SS + jt + vj0) * 1024 + h * 64 + vd0];
            short8 v0 = *(const short8*)vr;
            short8 v1 = *(const short8*)(vr + 1024);
#pragma unroll
            for (int e = 0; e < 8; ++e) {
                ushort2 pr;
                pr.x = (ushort)v0[e];
                pr.y = (ushort)v1[e];
                *(ushort2*)&Vt[(vd0 + e) * 72 + vj0] = pr;
            }
        }
        __syncthreads();
        floatx4 s[4] = {};
#pragma unroll
        for (int u = 0; u < 4; ++u) {
            short8 b0 = *(const short8*)&Ks[(u * 16 + c) * 72 + g * 8];
            short8 b1 = *(const short8*)&Ks[(u * 16 + c) * 72 + 32 + g * 8];
            s[u] = __builtin_amdgcn_mfma_f32_16x16x32_bf16(aq0, b0, s[u], 0, 0, 0);
            s[u] = __builtin_amdgcn_mfma_f32_16x16x32_bf16(aq1, b1, s[u], 0, 0, 0);
        }
        const bool full = (jt >= ibase - 240) && (jt <= ibase + 192);
#pragma unroll
        for (int u = 0; u < 4; ++u) {
#pragma unroll
            for (int r = 0; r < 4; ++r) {
                float v = s[u][r] * LOG2E;
                if (!full) {
                    const int i = ibase + g * 4 + r;
                    const int j = jt + u * 16 + c;
                    if ((unsigned)(i - j + 255) >= 511u) v = -3e38f;
                }
                float p = EXP2F(v - M[r]) * invL[r];
                Pl[w][(g * 4 + r) * 72 + u * 16 + c] = f2b(p);
            }
        }
        // write attn band tile (256B contiguous per row-quarter), nontemporal
#pragma unroll
        for (int it = 0; it < 4; ++it) {
            const int row = it * 4 + g;
            ushort4 pw = *(const ushort4*)&Pl[w][row * 72 + c * 4];
            floatx4 o;
            o[0] = b2f(pw.x); o[1] = b2f(pw.y); o[2] = b2f(pw.z); o[3] = b2f(pw.w);
            __builtin_nontemporal_store(o,
                (floatx4*)&attn[(size_t)(b * HH + h) * SS * SS + (size_t)(ibase + row) * SS + jt + c * 4]);
        }
        // PV: ctx += P @ V
#pragma unroll
        for (int jc = 0; jc < 2; ++jc) {
            short8 pa = *(const short8*)&Pl[w][c * 72 + jc * 32 + g * 8];
#pragma unroll
            for (int ds = 0; ds < 4; ++ds) {
                short8 bv_ = *(const short8*)&Vt[(ds * 16 + c) * 72 + jc * 32 + g * 8];
                ctx[ds] = __builtin_amdgcn_mfma_f32_16x16x32_bf16(pa, bv_, ctx[ds], 0, 0, 0);
            }
        }
    }

    // ---- ctx out (bf16) ----
#pragma unroll
    for (int ds = 0; ds < 4; ++ds)
#pragma unroll
        for (int r = 0; r < 4; ++r)
            ctxb[(size_t)(b * SS + ibase + g * 4 + r) * 1024 + h * 64 + ds * 16 + c] = f2b(ctx[ds][r]);

    // ---- zero-fill attn outside [jstart, jend), nontemporal ----
    {
        float* ab = attn + (size_t)(b * HH + h) * SS * SS;
        const floatx4 z4 = {0.f, 0.f, 0.f, 0.f};
        const int g16 = t >> 4, c16 = t & 15;
#pragma unroll
        for (int rr = 0; rr < 4; ++rr) {
            float* rp = ab + (size_t)(i0 + g16 + rr * 16) * SS;
            for (int x = c16 * 4; x < jstart; x += 64)
                __builtin_nontemporal_store(z4, (floatx4*)&rp[x]);
            for (int x = jend + c16 * 4; x < SS; x += 64)
                __builtin_nontemporal_store(z4, (floatx4*)&rp[x]);
        }
    }
}

// ---------------- residual + LayerNorm ----------------
__global__ __launch_bounds__(256) void ln_kernel(
    const float* __restrict__ op, const float* __restrict__ Qin,
    const float* __restrict__ gamma, const float* __restrict__ beta,
    float* __restrict__ y)
{
    const int row = blockIdx.x;
    const int t = threadIdx.x;
    __shared__ float rs[4], rss[4];

    float4 o4 = *(const float4*)&op[(size_t)row * 1024 + t * 4];
    float4 q4 = *(const float4*)&Qin[(size_t)row * 1024 + t * 4];
    float x0 = o4.x + q4.x, x1 = o4.y + q4.y, x2 = o4.z + q4.z, x3 = o4.w + q4.w;
    float s = x0 + x1 + x2 + x3;
    float ss = x0 * x0 + x1 * x1 + x2 * x2 + x3 * x3;
#pragma unroll
    for (int off = 1; off < 64; off <<= 1) {
        s  += __shfl_xor(s, off, 64);
        ss += __shfl_xor(ss, off, 64);
    }
    int wid = t >> 6;
    if ((t & 63) == 0) { rs[wid] = s; rss[wid] = ss; }
    __syncthreads();
    s  = rs[0] + rs[1] + rs[2] + rs[3];
    ss = rss[0] + rss[1] + rss[2] + rss[3];
    float mu = s * (1.0f / 1024.0f);
    float var = ss * (1.0f / 1024.0f) - mu * mu;
    float rstd = rsqrtf(var + LN_EPS);
    float4 g4 = *(const float4*)&gamma[t * 4];
    float4 b4 = *(const float4*)&beta[t * 4];
    float4 o;
    o.x = (x0 - mu) * rstd * g4.x + b4.x;
    o.y = (x1 - mu) * rstd * g4.y + b4.y;
    o.z = (x2 - mu) * rstd * g4.z + b4.z;
    o.w = (x3 - mu) * rstd * g4.w + b4.w;
    *(float4*)&y[(size_t)row * 1024 + t * 4] = o;
}

extern "C" void kernel_launch(void* const* d_in, const int* in_sizes, int n_in,
                              void* d_out, int out_size, void* d_ws, size_t ws_size,
                              hipStream_t stream) {
    (void)in_sizes; (void)n_in; (void)out_size; (void)ws_size;
    const float* Q  = (const float*)d_in[0];
    const float* K  = (const float*)d_in[1];
    const float* V  = (const float*)d_in[2];
    const float* Wq = (const float*)d_in[3];
    const float* bq = (const float*)d_in[4];
    const float* Wk = (const float*)d_in[5];
    const float* bk = (const float*)d_in[6];
    const float* Wv = (const float*)d_in[7];
    const float* bv = (const float*)d_in[8];
    const float* Wo = (const float*)d_in[9];
    const float* bo = (const float*)d_in[10];
    const float* gamma = (const float*)d_in[11];
    const float* beta  = (const float*)d_in[12];

    float* y = (float*)d_out;
    float* attn = y + (size_t)BB * SS * 1024;

    float* op = (float*)d_ws;                       // 4,194,304 floats
    ushort* ub = (ushort*)(op + 4194304);
    ushort* qbp  = ub;                              // 4,194,304 u16 each
    ushort* kbp  = ub + (size_t)4194304;
    ushort* vbp  = ub + (size_t)2 * 4194304;
    ushort* ctxb = ub + (size_t)3 * 4194304;
    ushort* Wqt  = ub + (size_t)4 * 4194304;        // 1,048,576 u16 each
    ushort* Wkt  = Wqt + 1048576;
    ushort* Wvt  = Wkt + 1048576;
    ushort* Wot  = Wvt + 1048576;

    wtrans<<<dim3(32, 32, 4), 256, 0, stream>>>(Wq, Wk, Wv, Wo, Wqt, Wkt, Wvt, Wot);
    gemm_qkv<<<dim3(16, 32, 3), 256, 0, stream>>>(Q, K, V, Wqt, Wkt, Wvt, bq, bk, bv, qbp, kbp, vbp);
    attn_mfma<<<dim3(SS / 64, HH, BB), 256, 0, stream>>>(qbp, kbp, vbp, attn, ctxb);
    gemm_obf<<<dim3(16, 32), 256, 0, stream>>>(ctxb, Wot, bo, op);
    ln_kernel<<<4096, 256, 0, stream>>>(op, Q, gamma, beta, y);
}

// Round 7
// 232.037 us; speedup vs baseline: 5.5750x; 1.0321x over previous
//
#include <hip/hip_runtime.h>
#include <hip/hip_bf16.h>

#define BB 2
#define SS 2048
#define HH 16
#define LN_EPS 1e-5f
#define LOG2E 1.44269504088896f

typedef __attribute__((ext_vector_type(8))) short short8;
typedef __attribute__((ext_vector_type(4))) float floatx4;

#define EXP2F(x) __builtin_amdgcn_exp2f(x)
#define GLOAD16(g, l) __builtin_amdgcn_global_load_lds( \
    (const __attribute__((address_space(1))) void*)(g), \
    (__attribute__((address_space(3))) void*)(l), 16, 0, 0)

__device__ __forceinline__ ushort f2b(float f) {
    union { float f; unsigned u; } x; x.f = f;
    unsigned u = x.u;
    return (ushort)((u + 0x7FFFu + ((u >> 16) & 1u)) >> 16);
}
__device__ __forceinline__ float b2f(ushort u) {
    union { unsigned u; float f; } x; x.u = ((unsigned)u) << 16;
    return x.f;
}

// ---------------- fp32 -> bf16 convert (Q,K,V) ----------------
__global__ __launch_bounds__(256) void to_bf16(
    const float* __restrict__ X0, const float* __restrict__ X1, const float* __restrict__ X2,
    ushort* __restrict__ Y0, ushort* __restrict__ Y1, ushort* __restrict__ Y2)
{
    const int z = blockIdx.z;
    const float* X = z == 0 ? X0 : z == 1 ? X1 : X2;
    ushort* Y = z == 0 ? Y0 : z == 1 ? Y1 : Y2;
    const size_t i = ((size_t)blockIdx.x * 256 + threadIdx.x) * 8;
    float4 a = *(const float4*)&X[i];
    float4 b = *(const float4*)&X[i + 4];
    short8 o;
    o[0] = (short)f2b(a.x); o[1] = (short)f2b(a.y); o[2] = (short)f2b(a.z); o[3] = (short)f2b(a.w);
    o[4] = (short)f2b(b.x); o[5] = (short)f2b(b.y); o[6] = (short)f2b(b.z); o[7] = (short)f2b(b.w);
    *(short8*)&Y[i] = o;
}

// ---------------- W transpose+convert: T[n][k] = bf16(scale*W[k][n]) ----------------
__global__ __launch_bounds__(256) void wtrans(
    const float* __restrict__ W0, const float* __restrict__ W1,
    const float* __restrict__ W2, const float* __restrict__ W3,
    ushort* __restrict__ T0, ushort* __restrict__ T1,
    ushort* __restrict__ T2, ushort* __restrict__ T3)
{
    const int z = blockIdx.z;
    const float* W = z == 0 ? W0 : z == 1 ? W1 : z == 2 ? W2 : W3;
    ushort* T = z == 0 ? T0 : z == 1 ? T1 : z == 2 ? T2 : T3;
    const float scale = (z == 0) ? 0.125f : 1.0f;  // fold 1/sqrt(DK) into Wq
    __shared__ float ts[32][33];
    const int k0 = blockIdx.y * 32, n0 = blockIdx.x * 32;
    const int r = threadIdx.x >> 3, c4 = (threadIdx.x & 7) * 4;
    float4 v = *(const float4*)&W[(size_t)(k0 + r) * 1024 + n0 + c4];
    ts[r][c4 + 0] = v.x; ts[r][c4 + 1] = v.y; ts[r][c4 + 2] = v.z; ts[r][c4 + 3] = v.w;
    __syncthreads();
    ushort4 o;
    o.x = f2b(ts[c4 + 0][r] * scale); o.y = f2b(ts[c4 + 1][r] * scale);
    o.z = f2b(ts[c4 + 2][r] * scale); o.w = f2b(ts[c4 + 3][r] * scale);
    *(ushort4*)&T[(size_t)(n0 + r) * 1024 + k0 + c4] = o;
}

// ---------------- m97-style MFMA GEMM: 128x128 tile, BK=32, global_load_lds ----------------
__device__ __forceinline__ void gemm_body(
    const ushort* __restrict__ Ab, const ushort* __restrict__ Bt,
    const float* __restrict__ bias, float bscale,
    float* Cf, ushort* Cb, int m0, int n0)
{
    __shared__ ushort As[128 * 32];   // linear: row stride 32 (required by global_load_lds)
    __shared__ ushort Bs[128 * 32];
    const int t = threadIdx.x;
    const int l = t & 63;
    const int w = t >> 6;
    const int wm = w >> 1, wn = w & 1;

    floatx4 acc[4][4] = {};

    // chunk i = q*256 + w*64 + l ; row = i>>2, kchunk = i&3 (8 bf16 each)
    const int i0c = w * 64 + l;
    const int r0 = i0c >> 2, c0 = i0c & 3;
    const int i1c = 256 + i0c;
    const int r1 = i1c >> 2, c1 = i1c & 3;

    const ushort* gA0 = &Ab[(size_t)(m0 + r0) * 1024 + c0 * 8];
    const ushort* gA1 = &Ab[(size_t)(m0 + r1) * 1024 + c1 * 8];
    const ushort* gB0 = &Bt[(size_t)(n0 + r0) * 1024 + c0 * 8];
    const ushort* gB1 = &Bt[(size_t)(n0 + r1) * 1024 + c1 * 8];

    // wave-uniform LDS byte dests: call q covers chunks [q*256 + w*64, +64)
    char* lA = (char*)As;
    char* lB = (char*)Bs;
    const int d0 = (w * 64) * 16;
    const int d1 = (256 + w * 64) * 16;

    for (int k0 = 0; k0 < 1024; k0 += 32) {
        __syncthreads();
        GLOAD16(gA0 + k0, lA + d0);
        GLOAD16(gA1 + k0, lA + d1);
        GLOAD16(gB0 + k0, lB + d0);
        GLOAD16(gB1 + k0, lB + d1);
        __syncthreads();

        short8 af[4], bf[4];
#pragma unroll
        for (int m = 0; m < 4; ++m)
            af[m] = *(const short8*)&As[(wm * 64 + m * 16 + (l & 15)) * 32 + (l >> 4) * 8];
#pragma unroll
        for (int n = 0; n < 4; ++n)
            bf[n] = *(const short8*)&Bs[(wn * 64 + n * 16 + (l & 15)) * 32 + (l >> 4) * 8];
#pragma unroll
        for (int m = 0; m < 4; ++m)
#pragma unroll
            for (int n = 0; n < 4; ++n)
                acc[m][n] = __builtin_amdgcn_mfma_f32_16x16x32_bf16(af[m], bf[n], acc[m][n], 0, 0, 0);
    }

    const int cr = (l >> 4) * 4;
    const int cc = l & 15;
#pragma unroll
    for (int n = 0; n < 4; ++n) {
        int col = n0 + wn * 64 + n * 16 + cc;
        float bv = bias[col] * bscale;
#pragma unroll
        for (int m = 0; m < 4; ++m) {
            int row = m0 + wm * 64 + m * 16 + cr;
#pragma unroll
            for (int j = 0; j < 4; ++j) {
                float v = acc[m][n][j] + bv;
                if (Cf) Cf[(size_t)(row + j) * 1024 + col] = v;
                else    Cb[(size_t)(row + j) * 1024 + col] = f2b(v);
            }
        }
    }
}

// XCD-aware swizzle over 256 blocks: each XCD owns 4 contiguous m-panels x all 8 n-tiles
// (A 4x128x1024 bf16 = 1MB + B 2MB < 4MB private L2).
__device__ __forceinline__ void swz_mn(int& m0, int& n0) {
    int bid = blockIdx.x + (blockIdx.y << 3);   // 0..255
    int xcd = bid & 7, idx = bid >> 3;          // idx 0..31
    m0 = (xcd * 4 + (idx & 3)) * 128;
    n0 = (idx >> 2) * 128;
}

__global__ __launch_bounds__(256) void gemm_qkv(
    const ushort* __restrict__ Xq, const ushort* __restrict__ Xk, const ushort* __restrict__ Xv,
    const ushort* __restrict__ Wqt, const ushort* __restrict__ Wkt, const ushort* __restrict__ Wvt,
    const float* __restrict__ bq, const float* __restrict__ bk, const float* __restrict__ bv,
    ushort* __restrict__ qp, ushort* __restrict__ kp, ushort* __restrict__ vp)
{
    const int z = blockIdx.z;
    const ushort* A = z == 0 ? Xq : z == 1 ? Xk : Xv;
    const ushort* Bt = z == 0 ? Wqt : z == 1 ? Wkt : Wvt;
    const float* bias = z == 0 ? bq : z == 1 ? bk : bv;
    ushort* C = z == 0 ? qp : z == 1 ? kp : vp;
    float bscale = (z == 0) ? 0.125f : 1.0f;
    int m0, n0; swz_mn(m0, n0);
    gemm_body(A, Bt, bias, bscale, nullptr, C, m0, n0);
}

__global__ __launch_bounds__(256) void gemm_obf(
    const ushort* __restrict__ ctxb, const ushort* __restrict__ Wot,
    const float* __restrict__ bo, float* __restrict__ op)
{
    int m0, n0; swz_mn(m0, n0);
    gemm_body(ctxb, Wot, bo, 1.0f, op, nullptr, m0, n0);
}

// ---------------- MFMA banded attention: 64 q-rows/block, 4 waves x 16 rows ----------------
__global__ __launch_bounds__(256, 4) void attn_mfma(
    const ushort* __restrict__ qb, const ushort* __restrict__ kb, const ushort* __restrict__ vb,
    float* __restrict__ attn, ushort* __restrict__ ctxb)
{
    __shared__ alignas(16) ushort Ks[64 * 72];
    __shared__ alignas(16) ushort Vt[64 * 72];
    __shared__ alignas(16) ushort Pl[4][16 * 72];

    const int qblk = blockIdx.x, h = blockIdx.y, b = blockIdx.z;
    const int i0 = qblk * 64;
    const int t = threadIdx.x;
    const int w = t >> 6, l = t & 63;
    const int g = l >> 4, c = l & 15;
    const int ibase = i0 + w * 16;

    const int jstart = max(0, i0 - 256);            // 64-aligned
    const int jend = min(SS, i0 + 64 + 256);        // 64-aligned

    // Q A-fragments (rows ibase..ibase+15, pre-scaled via Wq)
    const size_t qoff = (size_t)(b * SS + ibase + c) * 1024 + h * 64 + g * 8;
    short8 aq0 = *(const short8*)&qb[qoff];
    short8 aq1 = *(const short8*)&qb[qoff + 32];

    const int krow = t >> 2, kd0 = (t & 3) * 16;
    const int vj0 = (t & 31) * 2, vd0 = (t >> 5) * 8;

    float m[4] = {-3e38f, -3e38f, -3e38f, -3e38f};
    float ll[4] = {0.f, 0.f, 0.f, 0.f};

    // ---- pass 1: running row max + sum (exp2 domain), in registers ----
    for (int jt = jstart; jt < jend; jt += 64) {
        __syncthreads();
        {
            const ushort* kr = &kb[(size_t)(b * SS + jt + krow) * 1024 + h * 64 + kd0];
            short8 k0 = *(const short8*)kr;
            short8 k1 = *(const short8*)(kr + 8);
            *(short8*)&Ks[krow * 72 + kd0] = k0;
            *(short8*)&Ks[krow * 72 + kd0 + 8] = k1;
        }
        __syncthreads();
        floatx4 s[4] = {};
#pragma unroll
        for (int u = 0; u < 4; ++u) {
            short8 b0 = *(const short8*)&Ks[(u * 16 + c) * 72 + g * 8];
            short8 b1 = *(const short8*)&Ks[(u * 16 + c) * 72 + 32 + g * 8];
            s[u] = __builtin_amdgcn_mfma_f32_16x16x32_bf16(aq0, b0, s[u], 0, 0, 0);
            s[u] = __builtin_amdgcn_mfma_f32_16x16x32_bf16(aq1, b1, s[u], 0, 0, 0);
        }
        const bool full = (jt >= ibase - 240) && (jt <= ibase + 192);
#pragma unroll
        for (int r = 0; r < 4; ++r) {
            float v0 = s[0][r] * LOG2E, v1 = s[1][r] * LOG2E,
                  v2 = s[2][r] * LOG2E, v3 = s[3][r] * LOG2E;
            if (!full) {
                const int i = ibase + g * 4 + r;
                const int j0 = jt + c;
                if ((unsigned)(i - j0 + 255) >= 511u)        v0 = -3e38f;
                if ((unsigned)(i - (j0 + 16) + 255) >= 511u) v1 = -3e38f;
                if ((unsigned)(i - (j0 + 32) + 255) >= 511u) v2 = -3e38f;
                if ((unsigned)(i - (j0 + 48) + 255) >= 511u) v3 = -3e38f;
            }
            float tmax = fmaxf(fmaxf(v0, v1), fmaxf(v2, v3));
            float mn = fmaxf(m[r], tmax);
            float sc_ = EXP2F(m[r] - mn);
            float add = EXP2F(v0 - mn) + EXP2F(v1 - mn)
                      + EXP2F(v2 - mn) + EXP2F(v3 - mn);
            ll[r] = ll[r] * sc_ + add;
            m[r] = mn;
        }
    }

    // ---- finalize softmax stats across the 16 j-lanes of each row ----
    float M[4], invL[4];
#pragma unroll
    for (int r = 0; r < 4; ++r) {
        float mm = m[r];
        mm = fmaxf(mm, __shfl_xor(mm, 1));
        mm = fmaxf(mm, __shfl_xor(mm, 2));
        mm = fmaxf(mm, __shfl_xor(mm, 4));
        mm = fmaxf(mm, __shfl_xor(mm, 8));
        float la = ll[r] * EXP2F(m[r] - mm);
        la += __shfl_xor(la, 1);
        la += __shfl_xor(la, 2);
        la += __shfl_xor(la, 4);
        la += __shfl_xor(la, 8);
        M[r] = mm;
        invL[r] = 1.0f / la;
    }

    // ---- pass 2: probs -> attn + PV ----
    floatx4 ctx[4] = {};
    for (int jt = jstart; jt < jend; jt += 64) {
        __syncthreads();
        {
            const ushort* kr = &kb[(size_t)(b * SS + jt + krow) * 1024 + h * 64 + kd0];
            short8 k0 = *(const short8*)kr;
            short8 k1 = *(const short8*)(kr + 8);
            *(short8*)&Ks[krow * 72 + kd0] = k0;
            *(short8*)&Ks[krow * 72 + kd0 + 8] = k1;
        }
        {
            const ushort* vr = &vb[(size_t)(b * SS + jt + vj0) * 1024 + h * 64 + vd0];
            short8 v0 = *(const short8*)vr;
            short8 v1 = *(const short8*)(vr + 1024);
#pragma unroll
            for (int e = 0; e < 8; ++e) {
                ushort2 pr;
                pr.x = (ushort)v0[e];
                pr.y = (ushort)v1[e];
                *(ushort2*)&Vt[(vd0 + e) * 72 + vj0] = pr;
            }
        }
        __syncthreads();
        floatx4 s[4] = {};
#pragma unroll
        for (int u = 0; u < 4; ++u) {
            short8 b0 = *(const short8*)&Ks[(u * 16 + c) * 72 + g * 8];
            short8 b1 = *(const short8*)&Ks[(u * 16 + c) * 72 + 32 + g * 8];
            s[u] = __builtin_amdgcn_mfma_f32_16x16x32_bf16(aq0, b0, s[u], 0, 0, 0);
            s[u] = __builtin_amdgcn_mfma_f32_16x16x32_bf16(aq1, b1, s[u], 0, 0, 0);
        }
        const bool full = (jt >= ibase - 240) && (jt <= ibase + 192);
#pragma unroll
        for (int u = 0; u < 4; ++u) {
#pragma unroll
            for (int r = 0; r < 4; ++r) {
                float v = s[u][r] * LOG2E;
                if (!full) {
                    const int i = ibase + g * 4 + r;
                    const int j = jt + u * 16 + c;
                    if ((unsigned)(i - j + 255) >= 511u) v = -3e38f;
                }
                float p = EXP2F(v - M[r]) * invL[r];
                Pl[w][(g * 4 + r) * 72 + u * 16 + c] = f2b(p);
            }
        }
        // write attn band tile (256B contiguous per row-quarter), nontemporal
#pragma unroll
        for (int it = 0; it < 4; ++it) {
            const int row = it * 4 + g;
            ushort4 pw = *(const ushort4*)&Pl[w][row * 72 + c * 4];
            floatx4 o;
            o[0] = b2f(pw.x); o[1] = b2f(pw.y); o[2] = b2f(pw.z); o[3] = b2f(pw.w);
            __builtin_nontemporal_store(o,
                (floatx4*)&attn[(size_t)(b * HH + h) * SS * SS + (size_t)(ibase + row) * SS + jt + c * 4]);
        }
        // PV: ctx += P @ V
#pragma unroll
        for (int jc = 0; jc < 2; ++jc) {
            short8 pa = *(const short8*)&Pl[w][c * 72 + jc * 32 + g * 8];
#pragma unroll
            for (int ds = 0; ds < 4; ++ds) {
                short8 bv_ = *(const short8*)&Vt[(ds * 16 + c) * 72 + jc * 32 + g * 8];
                ctx[ds] = __builtin_amdgcn_mfma_f32_16x16x32_bf16(pa, bv_, ctx[ds], 0, 0, 0);
            }
        }
    }

    // ---- ctx out (bf16) ----
#pragma unroll
    for (int ds = 0; ds < 4; ++ds)
#pragma unroll
        for (int r = 0; r < 4; ++r)
            ctxb[(size_t)(b * SS + ibase + g * 4 + r) * 1024 + h * 64 + ds * 16 + c] = f2b(ctx[ds][r]);

    // ---- zero-fill attn outside [jstart, jend), nontemporal ----
    {
        float* ab = attn + (size_t)(b * HH + h) * SS * SS;
        const floatx4 z4 = {0.f, 0.f, 0.f, 0.f};
        const int g16 = t >> 4, c16 = t & 15;
#pragma unroll
        for (int rr = 0; rr < 4; ++rr) {
            float* rp = ab + (size_t)(i0 + g16 + rr * 16) * SS;
            for (int x = c16 * 4; x < jstart; x += 64)
                __builtin_nontemporal_store(z4, (floatx4*)&rp[x]);
            for (int x = jend + c16 * 4; x < SS; x += 64)
                __builtin_nontemporal_store(z4, (floatx4*)&rp[x]);
        }
    }
}

// ---------------- residual + LayerNorm ----------------
__global__ __launch_bounds__(256) void ln_kernel(
    const float* __restrict__ op, const float* __restrict__ Qin,
    const float* __restrict__ gamma, const float* __restrict__ beta,
    float* __restrict__ y)
{
    const int row = blockIdx.x;
    const int t = threadIdx.x;
    __shared__ float rs[4], rss[4];

    float4 o4 = *(const float4*)&op[(size_t)row * 1024 + t * 4];
    float4 q4 = *(const float4*)&Qin[(size_t)row * 1024 + t * 4];
    float x0 = o4.x + q4.x, x1 = o4.y + q4.y, x2 = o4.z + q4.z, x3 = o4.w + q4.w;
    float s = x0 + x1 + x2 + x3;
    float ss = x0 * x0 + x1 * x1 + x2 * x2 + x3 * x3;
#pragma unroll
    for (int off = 1; off < 64; off <<= 1) {
        s  += __shfl_xor(s, off, 64);
        ss += __shfl_xor(ss, off, 64);
    }
    int wid = t >> 6;
    if ((t & 63) == 0) { rs[wid] = s; rss[wid] = ss; }
    __syncthreads();
    s  = rs[0] + rs[1] + rs[2] + rs[3];
    ss = rss[0] + rss[1] + rss[2] + rss[3];
    float mu = s * (1.0f / 1024.0f);
    float var = ss * (1.0f / 1024.0f) - mu * mu;
    float rstd = rsqrtf(var + LN_EPS);
    float4 g4 = *(const float4*)&gamma[t * 4];
    float4 b4 = *(const float4*)&beta[t * 4];
    float4 o;
    o.x = (x0 - mu) * rstd * g4.x + b4.x;
    o.y = (x1 - mu) * rstd * g4.y + b4.y;
    o.z = (x2 - mu) * rstd * g4.z + b4.z;
    o.w = (x3 - mu) * rstd * g4.w + b4.w;
    *(float4*)&y[(size_t)row * 1024 + t * 4] = o;
}

extern "C" void kernel_launch(void* const* d_in, const int* in_sizes, int n_in,
                              void* d_out, int out_size, void* d_ws, size_t ws_size,
                              hipStream_t stream) {
    (void)in_sizes; (void)n_in; (void)out_size; (void)ws_size;
    const float* Q  = (const float*)d_in[0];
    const float* K  = (const float*)d_in[1];
    const float* V  = (const float*)d_in[2];
    const float* Wq = (const float*)d_in[3];
    const float* bq = (const float*)d_in[4];
    const float* Wk = (const float*)d_in[5];
    const float* bk = (const float*)d_in[6];
    const float* Wv = (const float*)d_in[7];
    const float* bv = (const float*)d_in[8];
    const float* Wo = (const float*)d_in[9];
    const float* bo = (const float*)d_in[10];
    const float* gamma = (const float*)d_in[11];
    const float* beta  = (const float*)d_in[12];

    float* y = (float*)d_out;
    float* attn = y + (size_t)BB * SS * 1024;

    // workspace layout (bytes):
    //  [0,16M):  op (fp32)            -- aliased early by Xq (0-8M) + Xk (8-16M)
    //  [16M,24M): ctxb (bf16)         -- aliased early by Xv
    //  [24M,48M): qbp/kbp/vbp (bf16)
    //  [48M,56M): Wqt/Wkt/Wvt/Wot (bf16)
    char* base = (char*)d_ws;
    float*  op   = (float*)base;
    ushort* Xq   = (ushort*)base;                         // dead after gemm_qkv
    ushort* Xk   = (ushort*)(base + (size_t)8 * 1048576);
    ushort* Xv   = (ushort*)(base + (size_t)16 * 1048576);
    ushort* ctxb = (ushort*)(base + (size_t)16 * 1048576);
    ushort* qbp  = (ushort*)(base + (size_t)24 * 1048576);
    ushort* kbp  = (ushort*)(base + (size_t)32 * 1048576);
    ushort* vbp  = (ushort*)(base + (size_t)40 * 1048576);
    ushort* Wqt  = (ushort*)(base + (size_t)48 * 1048576);
    ushort* Wkt  = (ushort*)(base + (size_t)50 * 1048576);
    ushort* Wvt  = (ushort*)(base + (size_t)52 * 1048576);
    ushort* Wot  = (ushort*)(base + (size_t)54 * 1048576);

    to_bf16<<<dim3(2048, 1, 3), 256, 0, stream>>>(Q, K, V, Xq, Xk, Xv);
    wtrans<<<dim3(32, 32, 4), 256, 0, stream>>>(Wq, Wk, Wv, Wo, Wqt, Wkt, Wvt, Wot);
    gemm_qkv<<<dim3(8, 32, 3), 256, 0, stream>>>(Xq, Xk, Xv, Wqt, Wkt, Wvt, bq, bk, bv, qbp, kbp, vbp);
    attn_mfma<<<dim3(SS / 64, HH, BB), 256, 0, stream>>>(qbp, kbp, vbp, attn, ctxb);
    gemm_obf<<<dim3(8, 32), 256, 0, stream>>>(ctxb, Wot, bo, op);
    ln_kernel<<<4096, 256, 0, stream>>>(op, Q, gamma, beta, y);
}